// Round 1
// baseline (775.189 us; speedup 1.0000x reference)
//
#include <hip/hip_runtime.h>

typedef unsigned short u16;
typedef __bf16 bf16x8 __attribute__((ext_vector_type(8)));
typedef float f32x4 __attribute__((ext_vector_type(4)));

#define TOK 8192
#define DM 1024
#define HID 4096
#define RH 1024
#define NE 8
#define MAX_SLOTS 17408  // 16384 slots + 8*128 padding

__device__ __forceinline__ u16 f2bf(float f) {
  union { float f; unsigned u; } v; v.f = f;
  unsigned u = v.u;
  return (u16)((u + 0x7fffu + ((u >> 16) & 1u)) >> 16);  // RNE
}

struct alignas(8) U16x4 { u16 x, y, z, w; };

// ---------------- prep: casts / packs ----------------
__global__ __launch_bounds__(256) void k_cast4(const float4* __restrict__ in, U16x4* __restrict__ out, int n4) {
  int i = blockIdx.x * 256 + threadIdx.x;
  if (i >= n4) return;
  float4 v = in[i];
  out[i] = U16x4{f2bf(v.x), f2bf(v.y), f2bf(v.z), f2bf(v.w)};
}

// out row 2n = w1[n], row 2n+1 = w2[n]  (8192 x 1024)
__global__ __launch_bounds__(256) void k_pack_shared(const float4* __restrict__ w1, const float4* __restrict__ w2,
                                                     U16x4* __restrict__ out) {
  int i = blockIdx.x * 256 + threadIdx.x;  // 8192*256
  int row = i >> 8, c4 = i & 255;
  const float4* src = (row & 1) ? w2 : w1;
  float4 v = src[(size_t)(row >> 1) * 256 + c4];
  out[(size_t)row * 256 + c4] = U16x4{f2bf(v.x), f2bf(v.y), f2bf(v.z), f2bf(v.w)};
}

// per expert: out row 2n = w12[e][n] (h1), row 2n+1 = w12[e][1024+n] (h2)
__global__ __launch_bounds__(256) void k_pack_routed(const float4* __restrict__ w12, U16x4* __restrict__ out) {
  int i = blockIdx.x * 256 + threadIdx.x;  // 8*2048*256
  int c4 = i & 255;
  int row = (i >> 8) & 2047;
  int e = i >> 19;
  int srow = (row & 1) ? (1024 + (row >> 1)) : (row >> 1);
  float4 v = w12[((size_t)e * 2048 + srow) * 256 + c4];
  out[((size_t)e * 2048 + row) * 256 + c4] = U16x4{f2bf(v.x), f2bf(v.y), f2bf(v.z), f2bf(v.w)};
}

// ---------------- router: one wave per token ----------------
__global__ __launch_bounds__(256) void k_router(const float* __restrict__ x, const float* __restrict__ rw,
                                                const float* __restrict__ bias,
                                                int* __restrict__ tok_e, float* __restrict__ tok_g,
                                                int* __restrict__ counts) {
  int wave = threadIdx.x >> 6, lane = threadIdx.x & 63;
  int t = blockIdx.x * 4 + wave;
  const float4* xr = (const float4*)(x + (size_t)t * DM) + lane * 4;
  float4 xv[4];
#pragma unroll
  for (int j = 0; j < 4; j++) xv[j] = xr[j];
  float p[NE];
#pragma unroll
  for (int e = 0; e < NE; e++) {
    const float4* wr = (const float4*)(rw + (size_t)e * DM) + lane * 4;
    float s = 0.f;
#pragma unroll
    for (int j = 0; j < 4; j++) {
      float4 w = wr[j];
      s += xv[j].x * w.x + xv[j].y * w.y + xv[j].z * w.z + xv[j].w * w.w;
    }
    p[e] = s;
  }
#pragma unroll
  for (int e = 0; e < NE; e++) {
    float v = p[e];
#pragma unroll
    for (int off = 32; off; off >>= 1) v += __shfl_xor(v, off, 64);
    p[e] = v;
  }
  if (lane == 0) {
    float sc[NE];
#pragma unroll
    for (int e = 0; e < NE; e++) sc[e] = 1.f / (1.f + __expf(-p[e]));
    int e0 = 0; float b0 = sc[0] + bias[0];
#pragma unroll
    for (int e = 1; e < NE; e++) { float v = sc[e] + bias[e]; if (v > b0) { b0 = v; e0 = e; } }
    int e1 = -1; float b1 = -1e30f;
#pragma unroll
    for (int e = 0; e < NE; e++) { if (e == e0) continue; float v = sc[e] + bias[e]; if (v > b1) { b1 = v; e1 = e; } }
    tok_e[t * 2] = e0; tok_e[t * 2 + 1] = e1;
    tok_g[t * 2] = sc[e0]; tok_g[t * 2 + 1] = sc[e1];
    atomicAdd(&counts[e0], 1);
    atomicAdd(&counts[e1], 1);
  }
}

__global__ void k_offsets(const int* __restrict__ counts, int* __restrict__ offs) {
  int o = 0;
#pragma unroll
  for (int e = 0; e < NE; e++) {
    offs[e] = o;
    o += (counts[e] + 127) & ~127;  // 128-pad each expert bucket
  }
  offs[NE] = o;
}

__global__ __launch_bounds__(256) void k_init_slots(int* __restrict__ slot_token, float* __restrict__ slot_gate) {
  int i = blockIdx.x * 256 + threadIdx.x;
  if (i < MAX_SLOTS) { slot_token[i] = 0; slot_gate[i] = 0.f; }
}

__global__ __launch_bounds__(256) void k_assign(const int* __restrict__ tok_e, const float* __restrict__ tok_g,
                                                const int* __restrict__ offs, int* __restrict__ cursors,
                                                int* __restrict__ slot_token, float* __restrict__ slot_gate,
                                                int* __restrict__ token_slots) {
  int t = blockIdx.x * 256 + threadIdx.x;
  if (t >= TOK) return;
#pragma unroll
  for (int k = 0; k < 2; k++) {
    int e = tok_e[t * 2 + k];
    int pos = atomicAdd(&cursors[e], 1);
    int s = offs[e] + pos;
    slot_token[s] = t;
    slot_gate[s] = tok_g[t * 2 + k];
    token_slots[t * 2 + k] = s;
  }
}

// ---------------- GEMM: C = A @ B^T, 128x128 tile, BK=64, 4 waves ----------------
// EPI 1: SwiGLU-pair epilogue -> bf16, cols halved (even col=h1, odd=h2), optional gate
// EPI 2: plain fp32 store
#define AS1(p) ((__attribute__((address_space(1))) void*)(p))
#define AS3(p) ((__attribute__((address_space(3))) void*)(p))

template<int EPI, bool GROUPED, bool GATHER, bool GATE>
__global__ __launch_bounds__(256, 2) void gemm_bt(
    const u16* __restrict__ A, int lda,
    const u16* __restrict__ B, int ldb, size_t strideB,
    void* __restrict__ Cout, int ldc,
    int M, int N, int K,
    const int* __restrict__ slot_token,
    const float* __restrict__ slot_gate,
    const int* __restrict__ counts,
    const int* __restrict__ offs) {
  __shared__ alignas(16) u16 Al[128 * 64];
  __shared__ alignas(16) u16 Bl[128 * 64];
  const int tid = threadIdx.x;
  const int lane = tid & 63, wave = tid >> 6;
  const int nt = blockIdx.x, mt = blockIdx.y;
  int m0g;
  const u16* Bp = B;
  if (GROUPED) {
    const int e = blockIdx.z;
    int cnt = counts[e];
    if (mt * 128 >= cnt) return;  // block-uniform early exit
    m0g = offs[e] + mt * 128;
    Bp += (size_t)e * strideB;
  } else {
    m0g = mt * 128;
  }
  const int n0 = nt * 128;

  // staging source pointers. LDS dest is linear (wave-uniform base + lane*16B);
  // swizzle is applied on the GLOBAL source column so that reads can XOR-deswizzle.
  const u16* aSrc[4];
  const u16* bSrc[4];
#pragma unroll
  for (int j = 0; j < 4; j++) {
    int r = wave * 32 + j * 8 + (lane >> 3);
    int cg = (lane & 7) ^ (r & 7);
    int arow;
    if (GROUPED) {
      int slot = m0g + r;
      arow = GATHER ? slot_token[slot] : slot;
    } else {
      arow = m0g + r;
    }
    aSrc[j] = A + (size_t)arow * lda + cg * 8;
    bSrc[j] = Bp + (size_t)(n0 + r) * ldb + cg * 8;
  }

  f32x4 acc[4][4];
#pragma unroll
  for (int m = 0; m < 4; m++)
#pragma unroll
    for (int n = 0; n < 4; n++) acc[m][n] = (f32x4){0.f, 0.f, 0.f, 0.f};

  const int wm = wave >> 1, wn = wave & 1;
  const int KT = K >> 6;
  for (int kt = 0; kt < KT; ++kt) {
    __syncthreads();  // prev tile fully consumed
#pragma unroll
    for (int j = 0; j < 4; j++) {
      __builtin_amdgcn_global_load_lds(AS1(aSrc[j]), AS3(&Al[(wave * 32 + j * 8) * 64]), 16, 0, 0);
      __builtin_amdgcn_global_load_lds(AS1(bSrc[j]), AS3(&Bl[(wave * 32 + j * 8) * 64]), 16, 0, 0);
      aSrc[j] += 64; bSrc[j] += 64;
    }
    asm volatile("s_waitcnt vmcnt(0)" ::: "memory");
    __syncthreads();
#pragma unroll
    for (int ks = 0; ks < 2; ++ks) {
      bf16x8 af[4], bfv[4];
#pragma unroll
      for (int m = 0; m < 4; m++) {
        int row = wm * 64 + m * 16 + (lane & 15);
        int cg = ((lane >> 4) + ks * 4) ^ (row & 7);
        af[m] = *(const bf16x8*)&Al[row * 64 + cg * 8];
      }
#pragma unroll
      for (int n = 0; n < 4; n++) {
        int row = wn * 64 + n * 16 + (lane & 15);
        int cg = ((lane >> 4) + ks * 4) ^ (row & 7);
        bfv[n] = *(const bf16x8*)&Bl[row * 64 + cg * 8];
      }
#pragma unroll
      for (int m = 0; m < 4; m++)
#pragma unroll
        for (int n = 0; n < 4; n++)
          acc[m][n] = __builtin_amdgcn_mfma_f32_16x16x32_bf16(af[m], bfv[n], acc[m][n], 0, 0, 0);
    }
  }

  // epilogue. C/D layout: col = lane&15, row = (lane>>4)*4 + reg   [m89/m91]
  if (EPI == 2) {
    float* Cf = (float*)Cout;
#pragma unroll
    for (int m = 0; m < 4; m++) {
#pragma unroll
      for (int r = 0; r < 4; r++) {
        int row = wm * 64 + m * 16 + (lane >> 4) * 4 + r;
        size_t grow = (size_t)(m0g + row);
#pragma unroll
        for (int n = 0; n < 4; n++) {
          int col = n0 + wn * 64 + n * 16 + (lane & 15);
          Cf[grow * ldc + col] = acc[m][n][r];
        }
      }
    }
  } else {
    u16* Cb = (u16*)Cout;
#pragma unroll
    for (int m = 0; m < 4; m++) {
#pragma unroll
      for (int r = 0; r < 4; r++) {
        int row = wm * 64 + m * 16 + (lane >> 4) * 4 + r;
        int grow = m0g + row;
        float gate = 1.f;
        if (GATE) gate = slot_gate[grow];  // 0 on padded slots -> zeros
#pragma unroll
        for (int n = 0; n < 4; n++) {
          float v = acc[m][n][r];
          float o = __shfl_xor(v, 1, 64);  // partner column (all lanes execute)
          if (!(lane & 1)) {               // even col = h1, odd = h2
            float g = v / (1.f + __expf(-v)) * o * gate;
            int col = (n0 + wn * 64 + n * 16 + (lane & 15)) >> 1;
            Cb[(size_t)grow * ldc + col] = f2bf(g);
          }
        }
      }
    }
  }
}

// ---------------- combine: out[t] += rp[slot0] + rp[slot1] ----------------
__global__ __launch_bounds__(256) void k_combine(float4* __restrict__ out, const float4* __restrict__ rp,
                                                 const int* __restrict__ token_slots) {
  int i = blockIdx.x * 256 + threadIdx.x;  // TOK*256 float4 groups
  int t = i >> 8, c4 = i & 255;
  int s0 = token_slots[t * 2], s1 = token_slots[t * 2 + 1];
  float4 a = out[i];
  float4 b = rp[(size_t)s0 * 256 + c4];
  float4 c = rp[(size_t)s1 * 256 + c4];
  a.x += b.x + c.x; a.y += b.y + c.y; a.z += b.z + c.z; a.w += b.w + c.w;
  out[i] = a;
}

extern "C" void kernel_launch(void* const* d_in, const int* in_sizes, int n_in,
                              void* d_out, int out_size, void* d_ws, size_t ws_size,
                              hipStream_t stream) {
  const float* x    = (const float*)d_in[0];
  const float* w12  = (const float*)d_in[1];
  const float* w3   = (const float*)d_in[2];
  const float* sw1  = (const float*)d_in[3];
  const float* sw2  = (const float*)d_in[4];
  const float* sw3  = (const float*)d_in[5];
  const float* rw   = (const float*)d_in[6];
  const float* bias = (const float*)d_in[7];
  float* out = (float*)d_out;

  char* ws = (char*)d_ws;
  size_t off = 0;
  auto alloc = [&](size_t bytes) -> void* {
    void* p = ws + off;
    off += (bytes + 255) & ~(size_t)255;
    return p;
  };
  u16* xb   = (u16*)alloc((size_t)TOK * DM * 2);           // x bf16
  u16* wshu = (u16*)alloc((size_t)2 * HID * DM * 2);       // shared up, interleaved
  u16* wshd = (u16*)alloc((size_t)DM * HID * 2);           // shared down (B^T layout already)
  u16* wru  = (u16*)alloc((size_t)NE * 2 * RH * DM * 2);   // routed up, interleaved
  u16* wrd  = (u16*)alloc((size_t)NE * DM * RH * 2);       // routed down (B^T layout already)
  u16* gr   = (u16*)alloc((size_t)MAX_SLOTS * RH * 2);     // gated routed hidden (slot-major)
  void* gunion = alloc((size_t)MAX_SLOTS * RH * 4);        // union: g (67MB) then rp (71MB)
  u16* g    = (u16*)gunion;                                // shared gated hidden (TOK x HID)
  float* rp = (float*)gunion;                              // routed per-slot output
  int* cc      = (int*)alloc(64);                          // counts[8] + cursors[8]
  int* counts  = cc;
  int* cursors = cc + 8;
  int* offs    = (int*)alloc(16 * 4);
  int* tok_e   = (int*)alloc((size_t)TOK * 2 * 4);
  float* tok_g = (float*)alloc((size_t)TOK * 2 * 4);
  int* slot_token  = (int*)alloc((size_t)MAX_SLOTS * 4);
  float* slot_gate = (float*)alloc((size_t)MAX_SLOTS * 4);
  int* token_slots = (int*)alloc((size_t)TOK * 2 * 4);
  (void)in_sizes; (void)n_in; (void)out_size; (void)ws_size;

  hipMemsetAsync(cc, 0, 64, stream);
  k_cast4<<<8192, 256, 0, stream>>>((const float4*)x, (U16x4*)xb, TOK * DM / 4);
  k_pack_shared<<<8192, 256, 0, stream>>>((const float4*)sw1, (const float4*)sw2, (U16x4*)wshu);
  k_cast4<<<4096, 256, 0, stream>>>((const float4*)sw3, (U16x4*)wshd, DM * HID / 4);
  k_pack_routed<<<16384, 256, 0, stream>>>((const float4*)w12, (U16x4*)wru);
  k_cast4<<<8192, 256, 0, stream>>>((const float4*)w3, (U16x4*)wrd, NE * DM * RH / 4);
  k_init_slots<<<(MAX_SLOTS + 255) / 256, 256, 0, stream>>>(slot_token, slot_gate);
  k_router<<<TOK / 4, 256, 0, stream>>>(x, rw, bias, tok_e, tok_g, counts);
  k_offsets<<<1, 1, 0, stream>>>(counts, offs);
  k_assign<<<TOK / 256, 256, 0, stream>>>(tok_e, tok_g, offs, cursors, slot_token, slot_gate, token_slots);

  // shared up: (8192 x 8192 x 1024), SwiGLU epilogue -> g (8192 x 4096 bf16)
  gemm_bt<1, false, false, false><<<dim3(64, 64, 1), 256, 0, stream>>>(
      xb, DM, wshu, DM, 0, g, HID, TOK, 2 * HID, DM, nullptr, nullptr, nullptr, nullptr);
  // shared down: (8192 x 1024 x 4096) -> d_out fp32
  gemm_bt<2, false, false, false><<<dim3(8, 64, 1), 256, 0, stream>>>(
      g, HID, wshd, HID, 0, out, DM, TOK, DM, HID, nullptr, nullptr, nullptr, nullptr);
  // routed up (grouped, gathered): per-expert (cnt x 2048 x 1024), SwiGLU*gate -> gr bf16
  gemm_bt<1, true, true, true><<<dim3(16, 64, 8), 256, 0, stream>>>(
      xb, DM, wru, DM, (size_t)2 * RH * DM, gr, RH, 0, 2 * RH, DM, slot_token, slot_gate, counts, offs);
  // routed down (grouped, slot-contiguous): per-expert (cnt x 1024 x 1024) -> rp fp32
  gemm_bt<2, true, false, false><<<dim3(8, 64, 8), 256, 0, stream>>>(
      gr, RH, wrd, RH, (size_t)DM * RH, rp, DM, 0, DM, RH, nullptr, nullptr, counts, offs);

  k_combine<<<TOK, 256, 0, stream>>>((float4*)out, (const float4*)rp, token_slots);
}

// Round 2
// 540.415 us; speedup vs baseline: 1.4344x; 1.4344x over previous
//
#include <hip/hip_runtime.h>

typedef unsigned short u16;
typedef __bf16 bf16x8 __attribute__((ext_vector_type(8)));
typedef float f32x4 __attribute__((ext_vector_type(4)));

#define TOK 8192
#define DM 1024
#define HID 4096
#define RH 1024
#define NE 8
#define MAX_SLOTS 17408  // 16384 slots + 8*128 padding

__device__ __forceinline__ u16 f2bf(float f) {
  union { float f; unsigned u; } v; v.f = f;
  unsigned u = v.u;
  return (u16)((u + 0x7fffu + ((u >> 16) & 1u)) >> 16);  // RNE
}

struct alignas(8) U16x4 { u16 x, y, z, w; };

// ---------------- prep: casts / packs ----------------
__global__ __launch_bounds__(256) void k_cast4(const float4* __restrict__ in, U16x4* __restrict__ out, int n4) {
  int i = blockIdx.x * 256 + threadIdx.x;
  if (i >= n4) return;
  float4 v = in[i];
  out[i] = U16x4{f2bf(v.x), f2bf(v.y), f2bf(v.z), f2bf(v.w)};
}

// out row 2n = w1[n], row 2n+1 = w2[n]  (8192 x 1024)
__global__ __launch_bounds__(256) void k_pack_shared(const float4* __restrict__ w1, const float4* __restrict__ w2,
                                                     U16x4* __restrict__ out) {
  int i = blockIdx.x * 256 + threadIdx.x;  // 8192*256
  int row = i >> 8, c4 = i & 255;
  const float4* src = (row & 1) ? w2 : w1;
  float4 v = src[(size_t)(row >> 1) * 256 + c4];
  out[(size_t)row * 256 + c4] = U16x4{f2bf(v.x), f2bf(v.y), f2bf(v.z), f2bf(v.w)};
}

// per expert: out row 2n = w12[e][n] (h1), row 2n+1 = w12[e][1024+n] (h2)
__global__ __launch_bounds__(256) void k_pack_routed(const float4* __restrict__ w12, U16x4* __restrict__ out) {
  int i = blockIdx.x * 256 + threadIdx.x;  // 8*2048*256
  int c4 = i & 255;
  int row = (i >> 8) & 2047;
  int e = i >> 19;
  int srow = (row & 1) ? (1024 + (row >> 1)) : (row >> 1);
  float4 v = w12[((size_t)e * 2048 + srow) * 256 + c4];
  out[((size_t)e * 2048 + row) * 256 + c4] = U16x4{f2bf(v.x), f2bf(v.y), f2bf(v.z), f2bf(v.w)};
}

// ---------------- router: one wave per token, NO atomics ----------------
__global__ __launch_bounds__(256) void k_router(const float* __restrict__ x, const float* __restrict__ rw,
                                                const float* __restrict__ bias,
                                                int* __restrict__ tok_e, float* __restrict__ tok_g) {
  int wave = threadIdx.x >> 6, lane = threadIdx.x & 63;
  int t = blockIdx.x * 4 + wave;
  const float4* xr = (const float4*)(x + (size_t)t * DM) + lane * 4;
  float4 xv[4];
#pragma unroll
  for (int j = 0; j < 4; j++) xv[j] = xr[j];
  float p[NE];
#pragma unroll
  for (int e = 0; e < NE; e++) {
    const float4* wr = (const float4*)(rw + (size_t)e * DM) + lane * 4;
    float s = 0.f;
#pragma unroll
    for (int j = 0; j < 4; j++) {
      float4 w = wr[j];
      s += xv[j].x * w.x + xv[j].y * w.y + xv[j].z * w.z + xv[j].w * w.w;
    }
    p[e] = s;
  }
#pragma unroll
  for (int e = 0; e < NE; e++) {
    float v = p[e];
#pragma unroll
    for (int off = 32; off; off >>= 1) v += __shfl_xor(v, off, 64);
    p[e] = v;
  }
  if (lane == 0) {
    float sc[NE];
#pragma unroll
    for (int e = 0; e < NE; e++) sc[e] = 1.f / (1.f + __expf(-p[e]));
    int e0 = 0; float b0 = sc[0] + bias[0];
#pragma unroll
    for (int e = 1; e < NE; e++) { float v = sc[e] + bias[e]; if (v > b0) { b0 = v; e0 = e; } }
    int e1 = -1; float b1 = -1e30f;
#pragma unroll
    for (int e = 0; e < NE; e++) { if (e == e0) continue; float v = sc[e] + bias[e]; if (v > b1) { b1 = v; e1 = e; } }
    tok_e[t * 2] = e0; tok_e[t * 2 + 1] = e1;
    tok_g[t * 2] = sc[e0]; tok_g[t * 2 + 1] = sc[e1];
  }
}

// ---------------- count: per-block LDS histogram, 8 global atomics/block ----------------
__global__ __launch_bounds__(256) void k_count(const int* __restrict__ tok_e, int* __restrict__ counts) {
  __shared__ int cnt[NE];
  int tid = threadIdx.x;
  if (tid < NE) cnt[tid] = 0;
  __syncthreads();
  int t = blockIdx.x * 256 + tid;  // 32 blocks x 256 = 8192
  atomicAdd(&cnt[tok_e[t * 2]], 1);
  atomicAdd(&cnt[tok_e[t * 2 + 1]], 1);
  __syncthreads();
  if (tid < NE) atomicAdd(&counts[tid], cnt[tid]);
}

__global__ void k_offsets(const int* __restrict__ counts, int* __restrict__ offs) {
  int o = 0;
#pragma unroll
  for (int e = 0; e < NE; e++) {
    offs[e] = o;
    o += (counts[e] + 127) & ~127;  // 128-pad each expert bucket
  }
  offs[NE] = o;
}

__global__ __launch_bounds__(256) void k_init_slots(int* __restrict__ slot_token, float* __restrict__ slot_gate) {
  int i = blockIdx.x * 256 + threadIdx.x;
  if (i < MAX_SLOTS) { slot_token[i] = 0; slot_gate[i] = 0.f; }
}

// ---------------- assign: two-level (LDS rank + one global atomic per expert per block) ----------------
__global__ __launch_bounds__(256) void k_assign(const int* __restrict__ tok_e, const float* __restrict__ tok_g,
                                                const int* __restrict__ offs, int* __restrict__ cursors,
                                                int* __restrict__ slot_token, float* __restrict__ slot_gate,
                                                int* __restrict__ token_slots) {
  __shared__ int lcnt[NE];
  __shared__ int base[NE];
  int tid = threadIdx.x;
  if (tid < NE) lcnt[tid] = 0;
  __syncthreads();
  int t = blockIdx.x * 256 + tid;  // 32 blocks x 256 = 8192
  int e0 = tok_e[t * 2], e1 = tok_e[t * 2 + 1];
  int r0 = atomicAdd(&lcnt[e0], 1);
  int r1 = atomicAdd(&lcnt[e1], 1);
  __syncthreads();
  if (tid < NE) base[tid] = atomicAdd(&cursors[tid], lcnt[tid]);
  __syncthreads();
  int s0 = offs[e0] + base[e0] + r0;
  int s1 = offs[e1] + base[e1] + r1;
  slot_token[s0] = t;
  slot_gate[s0] = tok_g[t * 2];
  token_slots[t * 2] = s0;
  slot_token[s1] = t;
  slot_gate[s1] = tok_g[t * 2 + 1];
  token_slots[t * 2 + 1] = s1;
}

// ---------------- GEMM: C = A @ B^T, 128x128 tile, BK=64, 4 waves ----------------
// EPI 1: SwiGLU-pair epilogue -> bf16, cols halved (even col=h1, odd=h2), optional gate
// EPI 2: plain fp32 store
#define AS1(p) ((__attribute__((address_space(1))) void*)(p))
#define AS3(p) ((__attribute__((address_space(3))) void*)(p))

template<int EPI, bool GROUPED, bool GATHER, bool GATE>
__global__ __launch_bounds__(256, 2) void gemm_bt(
    const u16* __restrict__ A, int lda,
    const u16* __restrict__ B, int ldb, size_t strideB,
    void* __restrict__ Cout, int ldc,
    int M, int N, int K,
    const int* __restrict__ slot_token,
    const float* __restrict__ slot_gate,
    const int* __restrict__ counts,
    const int* __restrict__ offs) {
  __shared__ alignas(16) u16 Al[128 * 64];
  __shared__ alignas(16) u16 Bl[128 * 64];
  const int tid = threadIdx.x;
  const int lane = tid & 63, wave = tid >> 6;
  const int nt = blockIdx.x, mt = blockIdx.y;
  int m0g;
  const u16* Bp = B;
  if (GROUPED) {
    const int e = blockIdx.z;
    int cnt = counts[e];
    if (mt * 128 >= cnt) return;  // block-uniform early exit
    m0g = offs[e] + mt * 128;
    Bp += (size_t)e * strideB;
  } else {
    m0g = mt * 128;
  }
  const int n0 = nt * 128;

  // staging source pointers. LDS dest is linear (wave-uniform base + lane*16B);
  // swizzle is applied on the GLOBAL source column so that reads can XOR-deswizzle.
  const u16* aSrc[4];
  const u16* bSrc[4];
#pragma unroll
  for (int j = 0; j < 4; j++) {
    int r = wave * 32 + j * 8 + (lane >> 3);
    int cg = (lane & 7) ^ (r & 7);
    int arow;
    if (GROUPED) {
      int slot = m0g + r;
      arow = GATHER ? slot_token[slot] : slot;
    } else {
      arow = m0g + r;
    }
    aSrc[j] = A + (size_t)arow * lda + cg * 8;
    bSrc[j] = Bp + (size_t)(n0 + r) * ldb + cg * 8;
  }

  f32x4 acc[4][4];
#pragma unroll
  for (int m = 0; m < 4; m++)
#pragma unroll
    for (int n = 0; n < 4; n++) acc[m][n] = (f32x4){0.f, 0.f, 0.f, 0.f};

  const int wm = wave >> 1, wn = wave & 1;
  const int KT = K >> 6;
  for (int kt = 0; kt < KT; ++kt) {
    __syncthreads();  // prev tile fully consumed
#pragma unroll
    for (int j = 0; j < 4; j++) {
      __builtin_amdgcn_global_load_lds(AS1(aSrc[j]), AS3(&Al[(wave * 32 + j * 8) * 64]), 16, 0, 0);
      __builtin_amdgcn_global_load_lds(AS1(bSrc[j]), AS3(&Bl[(wave * 32 + j * 8) * 64]), 16, 0, 0);
      aSrc[j] += 64; bSrc[j] += 64;
    }
    asm volatile("s_waitcnt vmcnt(0)" ::: "memory");
    __syncthreads();
#pragma unroll
    for (int ks = 0; ks < 2; ++ks) {
      bf16x8 af[4], bfv[4];
#pragma unroll
      for (int m = 0; m < 4; m++) {
        int row = wm * 64 + m * 16 + (lane & 15);
        int cg = ((lane >> 4) + ks * 4) ^ (row & 7);
        af[m] = *(const bf16x8*)&Al[row * 64 + cg * 8];
      }
#pragma unroll
      for (int n = 0; n < 4; n++) {
        int row = wn * 64 + n * 16 + (lane & 15);
        int cg = ((lane >> 4) + ks * 4) ^ (row & 7);
        bfv[n] = *(const bf16x8*)&Bl[row * 64 + cg * 8];
      }
#pragma unroll
      for (int m = 0; m < 4; m++)
#pragma unroll
        for (int n = 0; n < 4; n++)
          acc[m][n] = __builtin_amdgcn_mfma_f32_16x16x32_bf16(af[m], bfv[n], acc[m][n], 0, 0, 0);
    }
  }

  // epilogue. C/D layout: col = lane&15, row = (lane>>4)*4 + reg   [m89/m91]
  if (EPI == 2) {
    float* Cf = (float*)Cout;
#pragma unroll
    for (int m = 0; m < 4; m++) {
#pragma unroll
      for (int r = 0; r < 4; r++) {
        int row = wm * 64 + m * 16 + (lane >> 4) * 4 + r;
        size_t grow = (size_t)(m0g + row);
#pragma unroll
        for (int n = 0; n < 4; n++) {
          int col = n0 + wn * 64 + n * 16 + (lane & 15);
          Cf[grow * ldc + col] = acc[m][n][r];
        }
      }
    }
  } else {
    u16* Cb = (u16*)Cout;
#pragma unroll
    for (int m = 0; m < 4; m++) {
#pragma unroll
      for (int r = 0; r < 4; r++) {
        int row = wm * 64 + m * 16 + (lane >> 4) * 4 + r;
        int grow = m0g + row;
        float gate = 1.f;
        if (GATE) gate = slot_gate[grow];  // 0 on padded slots -> zeros
#pragma unroll
        for (int n = 0; n < 4; n++) {
          float v = acc[m][n][r];
          float o = __shfl_xor(v, 1, 64);  // partner column (all lanes execute)
          if (!(lane & 1)) {               // even col = h1, odd = h2
            float g = v / (1.f + __expf(-v)) * o * gate;
            int col = (n0 + wn * 64 + n * 16 + (lane & 15)) >> 1;
            Cb[(size_t)grow * ldc + col] = f2bf(g);
          }
        }
      }
    }
  }
}

// ---------------- combine: out[t] += rp[slot0] + rp[slot1] ----------------
__global__ __launch_bounds__(256) void k_combine(float4* __restrict__ out, const float4* __restrict__ rp,
                                                 const int* __restrict__ token_slots) {
  int i = blockIdx.x * 256 + threadIdx.x;  // TOK*256 float4 groups
  int t = i >> 8, c4 = i & 255;
  int s0 = token_slots[t * 2], s1 = token_slots[t * 2 + 1];
  float4 a = out[i];
  float4 b = rp[(size_t)s0 * 256 + c4];
  float4 c = rp[(size_t)s1 * 256 + c4];
  a.x += b.x + c.x; a.y += b.y + c.y; a.z += b.z + c.z; a.w += b.w + c.w;
  out[i] = a;
}

extern "C" void kernel_launch(void* const* d_in, const int* in_sizes, int n_in,
                              void* d_out, int out_size, void* d_ws, size_t ws_size,
                              hipStream_t stream) {
  const float* x    = (const float*)d_in[0];
  const float* w12  = (const float*)d_in[1];
  const float* w3   = (const float*)d_in[2];
  const float* sw1  = (const float*)d_in[3];
  const float* sw2  = (const float*)d_in[4];
  const float* sw3  = (const float*)d_in[5];
  const float* rw   = (const float*)d_in[6];
  const float* bias = (const float*)d_in[7];
  float* out = (float*)d_out;

  char* ws = (char*)d_ws;
  size_t off = 0;
  auto alloc = [&](size_t bytes) -> void* {
    void* p = ws + off;
    off += (bytes + 255) & ~(size_t)255;
    return p;
  };
  u16* xb   = (u16*)alloc((size_t)TOK * DM * 2);           // x bf16
  u16* wshu = (u16*)alloc((size_t)2 * HID * DM * 2);       // shared up, interleaved
  u16* wshd = (u16*)alloc((size_t)DM * HID * 2);           // shared down (B^T layout already)
  u16* wru  = (u16*)alloc((size_t)NE * 2 * RH * DM * 2);   // routed up, interleaved
  u16* wrd  = (u16*)alloc((size_t)NE * DM * RH * 2);       // routed down (B^T layout already)
  u16* gr   = (u16*)alloc((size_t)MAX_SLOTS * RH * 2);     // gated routed hidden (slot-major)
  void* gunion = alloc((size_t)MAX_SLOTS * RH * 4);        // union: g (67MB) then rp (71MB)
  u16* g    = (u16*)gunion;                                // shared gated hidden (TOK x HID)
  float* rp = (float*)gunion;                              // routed per-slot output
  int* cc      = (int*)alloc(64);                          // counts[8] + cursors[8]
  int* counts  = cc;
  int* cursors = cc + 8;
  int* offs    = (int*)alloc(16 * 4);
  int* tok_e   = (int*)alloc((size_t)TOK * 2 * 4);
  float* tok_g = (float*)alloc((size_t)TOK * 2 * 4);
  int* slot_token  = (int*)alloc((size_t)MAX_SLOTS * 4);
  float* slot_gate = (float*)alloc((size_t)MAX_SLOTS * 4);
  int* token_slots = (int*)alloc((size_t)TOK * 2 * 4);
  (void)in_sizes; (void)n_in; (void)out_size; (void)ws_size;

  hipMemsetAsync(cc, 0, 64, stream);
  k_cast4<<<8192, 256, 0, stream>>>((const float4*)x, (U16x4*)xb, TOK * DM / 4);
  k_pack_shared<<<8192, 256, 0, stream>>>((const float4*)sw1, (const float4*)sw2, (U16x4*)wshu);
  k_cast4<<<4096, 256, 0, stream>>>((const float4*)sw3, (U16x4*)wshd, DM * HID / 4);
  k_pack_routed<<<16384, 256, 0, stream>>>((const float4*)w12, (U16x4*)wru);
  k_cast4<<<8192, 256, 0, stream>>>((const float4*)w3, (U16x4*)wrd, NE * DM * RH / 4);
  k_init_slots<<<(MAX_SLOTS + 255) / 256, 256, 0, stream>>>(slot_token, slot_gate);
  k_router<<<TOK / 4, 256, 0, stream>>>(x, rw, bias, tok_e, tok_g);
  k_count<<<TOK / 256, 256, 0, stream>>>(tok_e, counts);
  k_offsets<<<1, 1, 0, stream>>>(counts, offs);
  k_assign<<<TOK / 256, 256, 0, stream>>>(tok_e, tok_g, offs, cursors, slot_token, slot_gate, token_slots);

  // shared up: (8192 x 8192 x 1024), SwiGLU epilogue -> g (8192 x 4096 bf16)
  gemm_bt<1, false, false, false><<<dim3(64, 64, 1), 256, 0, stream>>>(
      xb, DM, wshu, DM, 0, g, HID, TOK, 2 * HID, DM, nullptr, nullptr, nullptr, nullptr);
  // shared down: (8192 x 1024 x 4096) -> d_out fp32
  gemm_bt<2, false, false, false><<<dim3(8, 64, 1), 256, 0, stream>>>(
      g, HID, wshd, HID, 0, out, DM, TOK, DM, HID, nullptr, nullptr, nullptr, nullptr);
  // routed up (grouped, gathered): per-expert (cnt x 2048 x 1024), SwiGLU*gate -> gr bf16
  gemm_bt<1, true, true, true><<<dim3(16, 64, 8), 256, 0, stream>>>(
      xb, DM, wru, DM, (size_t)2 * RH * DM, gr, RH, 0, 2 * RH, DM, slot_token, slot_gate, counts, offs);
  // routed down (grouped, slot-contiguous): per-expert (cnt x 1024 x 1024) -> rp fp32
  gemm_bt<2, true, false, false><<<dim3(8, 64, 8), 256, 0, stream>>>(
      gr, RH, wrd, RH, (size_t)DM * RH, rp, DM, 0, DM, RH, nullptr, nullptr, counts, offs);

  k_combine<<<TOK, 256, 0, stream>>>((float4*)out, (const float4*)rp, token_slots);
}